// Round 16
// baseline (87.808 us; speedup 1.0000x reference)
//
#include <hip/hip_runtime.h>
#include <stdint.h>

#define A_DIM 8192
#define B_DIM 8192
#define K_CL  256
#define NSLAB 8
#define SLABW (B_DIM / NSLAB)   // 1024
#define NKS   (SLABW / 64)      // 16 K-steps of 64

typedef short bf16x8 __attribute__((ext_vector_type(8)));
typedef float f32x4  __attribute__((ext_vector_type(4)));
typedef float f32x16 __attribute__((ext_vector_type(16)));
typedef unsigned short u16;

__device__ __forceinline__ u16 f2bf(float f) {
    unsigned int u = __float_as_uint(f);
    u += 0x7fffu + ((u >> 16) & 1u);   // RNE (prep only)
    return (u16)(u >> 16);
}

// ---------- prep: pack p_r into 32x32x16 MFMA B-fragment layout, bf16 ----------
// Bpack[((kb2*8 + c2)*64 + lane)*8 + j] = bf16(p_r[kb2*16 + (lane>>5)*8 + j][c2*32 + (lane&31)])
__global__ __launch_bounds__(256) void k_prep(const float* __restrict__ pr,
                                              u16* __restrict__ Bpack,
                                              float* __restrict__ out) {
    const int kb2 = blockIdx.x;          // 0..511
    const int t = threadIdx.x;
    if (kb2 == 0 && t == 0) out[0] = 0.0f;
    const int lane = t & 63, wv = t >> 6;
    const int l31 = lane & 31, half = lane >> 5;
#pragma unroll
    for (int ci = 0; ci < 2; ci++) {
        const int c2 = wv * 2 + ci;
        float v[8];
#pragma unroll
        for (int j = 0; j < 8; j++)
            v[j] = pr[(size_t)(kb2 * 16 + half * 8 + j) * K_CL + c2 * 32 + l31];
        union { bf16x8 b; unsigned int u[4]; } o;
#pragma unroll
        for (int j = 0; j < 4; j++)
            o.u[j] = (unsigned int)f2bf(v[2 * j]) | ((unsigned int)f2bf(v[2 * j + 1]) << 16);
        *(bf16x8*)(Bpack + ((size_t)(kb2 * 8 + c2) * 64 + lane) * 8) = o.b;
    }
}

// ---------- main: barrier-free self-paced waves (r9 structure, exact B indexing) ----------
__global__ __launch_bounds__(256, 2) void k_main(const float* __restrict__ w,
                                                 const float* __restrict__ pl,
                                                 const u16* __restrict__ Bpack,
                                                 const float* __restrict__ cp,
                                                 float* __restrict__ out) {
    __shared__ u16 Abf[4][2][2048];      // per-wave private double buffer (4 KB each)
    __shared__ float rowsum_s[4][32];
    __shared__ float red[4];

    const int bid = blockIdx.x;
    const int slab = bid & 7;            // == XCD on round-robin dispatch -> Bpack slice L2-resident
    const int mt  = bid >> 3;
    const int tid = threadIdx.x;
    const int lane = tid & 63, wv = tid >> 6;
    const int l31 = lane & 31, half = lane >> 5;
    const int g4 = lane >> 4, c16 = lane & 15;

    const int m0w = mt * 128 + wv * 32;          // this wave's 32-row strip
    const size_t kbase = (size_t)slab * SLABW;
    const int kb2base = slab * 64;

    const float* wthr = w + (size_t)(m0w + g4) * B_DIM + kbase + c16 * 4;
    u16* lds = &Abf[wv][0][0];
    const int swz = (l31 & 7) << 4;

    f32x16 acc[8];
#pragma unroll
    for (int i = 0; i < 8; i++)
#pragma unroll
        for (int r = 0; r < 16; r++) acc[i][r] = 0.f;
    float sm[8] = {0.f, 0.f, 0.f, 0.f, 0.f, 0.f, 0.f, 0.f};

    f32x4 G[8];
    bf16x8 Bc[8], Bn[8];

#define WAIT8 do { asm volatile("s_waitcnt vmcnt(8)" ::: "memory"); __builtin_amdgcn_sched_barrier(0); } while (0)
#define WAIT0 do { asm volatile("s_waitcnt vmcnt(0)" ::: "memory"); __builtin_amdgcn_sched_barrier(0); } while (0)
#define LGKM0 do { asm volatile("s_waitcnt lgkmcnt(0)" ::: "memory"); __builtin_amdgcn_sched_barrier(0); } while (0)

#define GLOAD(ks) do {                                                                   \
        _Pragma("unroll")                                                                \
        for (int j_ = 0; j_ < 8; j_++)                                                   \
            G[j_] = *(const f32x4*)(wthr + (size_t)(4 * j_) * B_DIM + (size_t)(ks) * 64);\
    } while (0)

// exact Bpack addressing: frag(kb2, c2) at u16 offset (kb2*8 + c2)*512 + lane*8
#define LOADB(arr, s_, kf_) do {                                                         \
        const u16* bp_ = Bpack + (size_t)(kb2base + (s_) * 4 + (kf_)) * 4096 + lane * 8; \
        _Pragma("unroll")                                                                \
        for (int n2_ = 0; n2_ < 8; n2_++)                                                \
            (arr)[n2_] = *(const bf16x8*)(bp_ + n2_ * 512);                              \
    } while (0)

#define PERM2(hi, lo) __builtin_amdgcn_perm(__float_as_uint(hi), __float_as_uint(lo), 0x07060302u)

#define CONVERT(bufsel) do {                                                             \
        char* lb_ = (char*)lds + (bufsel) * 4096;                                        \
        _Pragma("unroll")                                                                \
        for (int j_ = 0; j_ < 8; j_++) {                                                 \
            sm[j_] += G[j_][0] + G[j_][1] + G[j_][2] + G[j_][3];                         \
            uint2 pj_;                                                                   \
            pj_.x = PERM2(G[j_][1], G[j_][0]);                                           \
            pj_.y = PERM2(G[j_][3], G[j_][2]);                                           \
            *(uint2*)(lb_ + (512 * j_ + 128 * g4)                                        \
                          + ((c16 * 8) ^ (g4 << 4) ^ ((j_ & 1) << 6))) = pj_;            \
        }                                                                                \
    } while (0)

#define KFSTEP(kf_, bufsel, Barr) do {                                                   \
        bf16x8 a_ = *(const bf16x8*)((const char*)lds + (bufsel) * 4096 + l31 * 128      \
                                     + (((kf_) * 32 + half * 16) ^ swz));                \
        __builtin_amdgcn_s_setprio(1);                                                   \
        _Pragma("unroll")                                                                \
        for (int n2_ = 0; n2_ < 8; n2_++)                                                \
            acc[n2_] = __builtin_amdgcn_mfma_f32_32x32x16_bf16(a_, (Barr)[n2_],          \
                                                               acc[n2_], 0, 0, 0);       \
        __builtin_amdgcn_s_setprio(0);                                                   \
    } while (0)

    // prologue: stage tile 0, start G(1) and B(0,0)
    GLOAD(0);
    WAIT0;
    CONVERT(0);
    GLOAD(1);              // queue: [G1:8]
    LOADB(Bc, 0, 0);       // queue: [G1:8][B00:8]
    LGKM0;

    for (int s = 0; s < NKS - 1; ++s) {      // s = 0..14
        const int buf = s & 1;
        LOADB(Bn, s, 1);      WAIT8; KFSTEP(0, buf, Bc);
        LOADB(Bc, s, 2);      WAIT8; KFSTEP(1, buf, Bn);
        LOADB(Bn, s, 3);      WAIT8; KFSTEP(2, buf, Bc);
        LOADB(Bc, s + 1, 0);  WAIT8; KFSTEP(3, buf, Bn);
        CONVERT(buf ^ 1);                    // G(s+1) was drained at kf0's WAIT8
        if (s < NKS - 2) GLOAD(s + 2);
        LGKM0;
    }
    // final step s = 15, buf = 1, no prefetch beyond slab
    LOADB(Bn, 15, 1); WAIT8; KFSTEP(0, 1, Bc);
    LOADB(Bc, 15, 2); WAIT8; KFSTEP(1, 1, Bn);
    LOADB(Bn, 15, 3); WAIT8; KFSTEP(2, 1, Bc);
    WAIT0;                   KFSTEP(3, 1, Bn);

#undef KFSTEP
#undef CONVERT
#undef PERM2
#undef LOADB
#undef GLOAD

    // per-wave row sums: sm[j] holds cols c16*4..+3 of row 4j+g4; reduce over c16
    {
#pragma unroll
        for (int j = 0; j < 8; j++) {
            float v = sm[j];
            v += __shfl_xor(v, 1, 64);
            v += __shfl_xor(v, 2, 64);
            v += __shfl_xor(v, 4, 64);
            v += __shfl_xor(v, 8, 64);
            if (c16 == 0) rowsum_s[wv][4 * j + g4] = v;
        }
    }
    float rcp_cp[8];
#pragma unroll
    for (int n2 = 0; n2 < 8; n2++)
        rcp_cp[n2] = 1.0f / cp[n2 * 32 + l31];

    // epilogue: tot = sum over (row,col) of [q + p*(rs - 2q)] / cp
    // C/D 32x32: col = lane&31, row = (reg&3) + 8*(reg>>2) + 4*(lane>>5)
    float tot = 0.f;
#pragma unroll
    for (int reg = 0; reg < 16; reg++) {
        const int lrow = (reg & 3) + 8 * (reg >> 2) + 4 * half;
        const float rs = rowsum_s[wv][lrow];
        const float* plrow = pl + (size_t)(m0w + lrow) * K_CL + l31;
#pragma unroll
        for (int n2 = 0; n2 < 8; n2++) {
            const float q = acc[n2][reg];
            const float p = plrow[n2 * 32];
            tot += (q + p * (rs - 2.0f * q)) * rcp_cp[n2];
        }
    }
    for (int o = 32; o; o >>= 1) tot += __shfl_down(tot, o, 64);
    if (lane == 0) red[wv] = tot;
    __syncthreads();
    if (tid == 0) atomicAdd(out, red[0] + red[1] + red[2] + red[3]);

#undef WAIT8
#undef WAIT0
#undef LGKM0
}

extern "C" void kernel_launch(void* const* d_in, const int* in_sizes, int n_in,
                              void* d_out, int out_size, void* d_ws, size_t ws_size,
                              hipStream_t stream) {
    const float* w  = (const float*)d_in[0];
    const float* pl = (const float*)d_in[1];
    const float* pr = (const float*)d_in[2];
    const float* cp = (const float*)d_in[3];
    float* out = (float*)d_out;

    u16* Bpack = (u16*)d_ws;   // 4 MB

    k_prep<<<dim3(512), dim3(256), 0, stream>>>(pr, Bpack, out);
    k_main<<<dim3(64 * NSLAB), dim3(256), 0, stream>>>(w, pl, Bpack, cp, out);
}